// Round 6
// baseline (275.176 us; speedup 1.0000x reference)
//
#include <hip/hip_runtime.h>

// BilateralFilter: 8 x 1024 x 1024 x 3 fp32, D=9 (radius 4), sigma_color =
// sigma_space = 75, reflect padding, taps with dy*dy+dx*dx <= 16 (49 live).
//
// Round 6: single-variable A/B vs round 5 (151 us, VALUBusy 98%): replace
// v_exp_f32 with an 8-op full-rate exp2 (exact exponent splice + deg-3 poly,
// max rel err ~0.07%). Two-point fit of R1/R5 wave times gives
// T_exp ~ 27 cyc/wave64 (~47% of kernel time); if true this lands ~120 us,
// if false it regresses to ~170 us — diagnostic either way.

namespace {
constexpr int Himg = 1024;
constexpr int Wimg = 1024;
constexpr int CHN  = 3;
constexpr int RAD  = 4;

constexpr int BXT = 64;              // tile width (one wave-row)
constexpr int BYT = 4;               // 4 waves -> 4 output rows
constexpr int TW  = BXT + 2 * RAD;   // 72 px
constexpr int TH  = BYT + 2 * RAD;   // 12 rows
constexpr int NPX = TW * TH;         // 864 staged pixels

constexpr float LOG2E = 1.4426950408889634f;
constexpr float COEFF = -0.5f / (75.0f * 75.0f);   // sigma_color == sigma_space
constexpr float KC2   = COEFF * LOG2E;             // exp2-domain coefficient (<0)

typedef float f4 __attribute__((ext_vector_type(4)));
}

__device__ __forceinline__ int reflect_idx(int i, int n) {
    i = (i < 0) ? -i : i;
    return (i >= n) ? (2 * n - 2 - i) : i;
}

// exp2(x) for x in (-80, 0]: round-to-nearest-int via the 1.5*2^23 trick,
// deg-3 Taylor on f in [-0.5,0.5], exponent spliced by integer add.
// 8 full-rate VALU ops, no trans pipe. Max rel err ~7e-4.
__device__ __forceinline__ float fast_exp2(float x) {
    const float MAGIC = 12582912.0f;            // 1.5 * 2^23, low 9 bits clear
    const float t = x + MAGIC;                  // int(t) = 0x4B400000 + rint(x)
    const float n = t - MAGIC;                  // rint(x)
    const float f = x - n;                      // [-0.5, 0.5]
    float p = fmaf(f, 0.05550411f, 0.24022651f);
    p = fmaf(f, p, 0.69314718f);
    p = fmaf(f, p, 1.0f);                       // ~2^f
    const int e = __float_as_int(t) << 23;      // = rint(x) << 23 exactly
    return __int_as_float(__float_as_int(p) + e);
}

__global__ __launch_bounds__(256, 4)
void bilateral_kernel(const float* __restrict__ in, float* __restrict__ out) {
    __shared__ f4 tile[TH][TW];        // 12 x 72 x 16B = 13824 B

    const float SC     = sqrtf(-KC2);  // constant-folded; staged px = SC*v
    const float INV_SC = 1.0f / SC;

    const int tid = threadIdx.x;
    const int x0  = blockIdx.x * BXT;
    const int y0  = blockIdx.y * BYT;

    const float* __restrict__ img = in + (size_t)blockIdx.z * Himg * Wimg * CHN;

    // ---- stage RGBW tile (reflect halo): (r*SC, g*SC, b*SC, 1.0) ----
    for (int i = tid; i < NPX; i += 256) {
        const int row = i / TW;
        const int px  = i - row * TW;
        const int gy  = reflect_idx(y0 - RAD + row, Himg);
        const int gx  = reflect_idx(x0 - RAD + px,  Wimg);
        const float* p = img + ((size_t)gy * Wimg + gx) * CHN;
        f4 v;
        v.x = p[0] * SC;
        v.y = p[1] * SC;
        v.z = p[2] * SC;
        v.w = 1.0f;
        tile[row][px] = v;             // ds_write_b128
    }
    __syncthreads();

    // ---- one output pixel per thread ----
    const int tx = tid & 63;           // wave = one 64-px row
    const int ty = tid >> 6;

    const f4 c = tile[ty + RAD][tx + RAD];
    const float cx = c.x, cy = c.y, cz = c.z;

    f4 acc = (f4){0.0f, 0.0f, 0.0f, 0.0f};

#pragma unroll
    for (int dy = -RAD; dy <= RAD; ++dy) {
#pragma unroll
        for (int dx = -RAD; dx <= RAD; ++dx) {
            const int r2 = dy * dy + dx * dx;
            if (r2 > RAD * RAD) continue;          // compile-time pruned (49 live)

            const f4 nb = tile[ty + RAD + dy][tx + RAD + dx];  // ds_read_b128

            // L1 color distance on pre-scaled values; abs folds into adds
            const float diff = fabsf(nb.x - cx) + fabsf(nb.y - cy)
                             + fabsf(nb.z - cz);

            // w = exp2(-diff^2 + KC2*r2) via full-rate polynomial exp2
            const float w = fast_exp2(fmaf(diff, -diff, KC2 * (float)r2));

            acc += nb * w;             // RGB numerator + W-lane denominator
        }
    }

    const float inv = (1.0f / acc.w) * INV_SC;     // un-scale numerator
    const size_t o =
        ((size_t)(blockIdx.z * Himg + y0 + ty) * Wimg + (x0 + tx)) * CHN;
    out[o + 0] = acc.x * inv;
    out[o + 1] = acc.y * inv;
    out[o + 2] = acc.z * inv;
}

extern "C" void kernel_launch(void* const* d_in, const int* in_sizes, int n_in,
                              void* d_out, int out_size, void* d_ws, size_t ws_size,
                              hipStream_t stream) {
    const float* in = (const float*)d_in[0];
    float* out = (float*)d_out;

    const int B = in_sizes[0] / (Himg * Wimg * CHN);   // = 8

    dim3 grid(Wimg / BXT, Himg / BYT, B);              // 16 x 256 x 8
    dim3 block(256);
    bilateral_kernel<<<grid, block, 0, stream>>>(in, out);
}